// Round 2
// baseline (322.978 us; speedup 1.0000x reference)
//
#include <hip/hip_runtime.h>

// ---------------------------------------------------------------------------
// 2-layer GCN + global mean pool, MI355X (gfx950).
//   A_hat = D^{-1/2}(A+I)D^{-1/2}
//   G' = dinv*(X @ W1) fp16 [MFMA fp16];  H'' = dinv*relu(dinv*A_sum(G')+b1)
//   out = pool(dinv*A_sum(H'')) @ W2 + b2
// R12: column-panel aggregation for XCD-L2 locality.
//   Gh/Hh stored panel-major: 4 panels x 32 cols (64B per node per panel =
//   one cache line). agg kernels pin panel = blockIdx&3; with round-robin
//   bid->XCD each XCD gathers only from its 3.2MB panel -> L2-resident,
//   per-XCD reuse 6.4x (was 1.6x with full-row gathers). Line-touches per
//   edge unchanged (4 x 64B) so downside is bounded if mapping differs.
//   colidx is ushort (N<65536) + nontemporal loads (less L2 pollution).
//   Wave = 4 edge-slots x 16 col-lanes; reduce via 2 shfl_xor.
// ws_size is 256 MiB; we use ~28 MB.
// ---------------------------------------------------------------------------

#define D 128
#define NGRAPH 64
#define SCAN_B 1024
#define AGG_BLOCKS 2048   // 8192 waves = 32/CU; 512 blocks (2048 waves) per panel
#define NPAN 4            // panels; 32 cols = 64B per node per panel

typedef _Float16 h16x2 __attribute__((ext_vector_type(2)));
typedef _Float16 f16x8 __attribute__((ext_vector_type(8)));
typedef float    f32x4 __attribute__((ext_vector_type(4)));

__device__ __forceinline__ float2 h2f(unsigned u) {
    h16x2 h = __builtin_bit_cast(h16x2, u);
    return make_float2((float)h.x, (float)h.y);
}
__device__ __forceinline__ unsigned f2h(float x, float y) {
    h16x2 h;
    h.x = (_Float16)x;
    h.y = (_Float16)y;
    return __builtin_bit_cast(unsigned, h);
}

// --- diagnostic: all-zero output (ws too small) ----------------------------
__global__ void zero_out_kernel(float* __restrict__ out, int n) {
    int i = blockIdx.x * blockDim.x + threadIdx.x;
    if (i < n) out[i] = 0.f;
}

// --- Fused: W1->fp16 MFMA-B pack | degree count ----------------------------
// Blocks [0,8): pack WB. [8, 8+eb): count dst degrees.
__global__ __launch_bounds__(256) void pack_count_kernel(const float* __restrict__ W1,
                                                         _Float16* __restrict__ WB,
                                                         const int* __restrict__ ei,
                                                         int* __restrict__ deg,
                                                         int N, int E) {
    int b = (int)blockIdx.x;
    if (b < 8) {
        // WB[((kt*8+nt)*64+lane)*8+j] = W1[(kt*32+(lane>>4)*8+j)*D + nt*16+(lane&15)]
        int idx = b * 256 + (int)threadIdx.x;          // 0..2047
        int lane = idx & 63;
        int nt   = (idx >> 6) & 7;
        int kt   = idx >> 9;
        int col  = nt * 16 + (lane & 15);
        int krow = kt * 32 + (lane >> 4) * 8;
#pragma unroll
        for (int j = 0; j < 8; ++j)
            WB[idx * 8 + j] = (_Float16)W1[(krow + j) * D + col];
        return;
    }
    int e = (b - 8) * 256 + (int)threadIdx.x;
    if (e < E) {
        int d = ei[E + e];
        if (d >= 0 && d < N) atomicAdd(&deg[d], 1);
    }
}

// per-block scan of deg -> local exclusive prefix; also emits dinv.
__global__ __launch_bounds__(SCAN_B) void block_scan_kernel(const int* __restrict__ deg,
                                                            int* __restrict__ rowstart,
                                                            int* __restrict__ bsum,
                                                            float* __restrict__ dinv,
                                                            int N) {
    __shared__ int sc[SCAN_B];
    int t = threadIdx.x;
    int i = blockIdx.x * SCAN_B + t;
    int orig = (i < N) ? deg[i] : 0;
    int v = orig;
    sc[t] = v;
    __syncthreads();
    for (int off = 1; off < SCAN_B; off <<= 1) {
        int add = (t >= off) ? sc[t - off] : 0;
        __syncthreads();
        v += add;
        sc[t] = v;
        __syncthreads();
    }
    if (i < N) {
        rowstart[i] = v - orig;                      // local exclusive
        dinv[i]     = rsqrtf((float)orig + 1.0f);    // +1 self loop
    }
    if (t == SCAN_B - 1) bsum[blockIdx.x] = v;
}

// each block self-computes its bsum prefix (nblk<=64) -> no scan_sums kernel.
__global__ __launch_bounds__(SCAN_B) void finalize_scan_kernel(const int* __restrict__ bsum,
                                                               int* __restrict__ rowstart,
                                                               int* __restrict__ cursor,
                                                               int N, int nblk, int E) {
    __shared__ int s_off;
    if (threadIdx.x < 64) {
        int lane = (int)threadIdx.x;
        int v = (lane < nblk && lane < (int)blockIdx.x) ? bsum[lane] : 0;
        for (int off = 32; off > 0; off >>= 1) v += __shfl_down(v, off);
        if (lane == 0) s_off = v;
    }
    __syncthreads();
    int i = blockIdx.x * SCAN_B + threadIdx.x;
    if (i < N) {
        int rs = rowstart[i] + s_off;
        rowstart[i] = rs;
        cursor[i]   = rs;
    }
    if (blockIdx.x == 0 && threadIdx.x == 0) rowstart[N] = E;
}

// --- Fused MFMA GEMM + fill -------------------------------------------------
// Blocks [0,gb): G' = dinv*(X @ W1h) via mfma_f32_16x16x32_f16, fp16 out,
//   written PANEL-MAJOR: Gp[(p*N + row)*32 + (nt&1)*16 + c16], p = nt>>1.
//   A-frag converted fp32->fp16 in-register (no staging pass).
// Blocks [gb,gb+eb): CSR fill (ushort colidx).
__global__ __launch_bounds__(256) void gemm_fill_kernel(const float* __restrict__ X,
                                                        const _Float16* __restrict__ WB,
                                                        const float* __restrict__ dinv,
                                                        _Float16* __restrict__ Gp,
                                                        const int* __restrict__ ei,
                                                        int* __restrict__ cursor,
                                                        unsigned short* __restrict__ colidx,
                                                        int N, int E, int gb) {
    if ((int)blockIdx.x >= gb) {
        int e = ((int)blockIdx.x - gb) * 256 + (int)threadIdx.x;
        if (e < E) {
            int d = ei[E + e];
            if (d >= 0 && d < N) {
                int slot = atomicAdd(&cursor[d], 1);
                if (slot >= 0 && slot < E) {
                    int s = ei[e];
                    colidx[slot] = (unsigned short)min(max(s, 0), N - 1);
                }
            }
        }
        return;
    }

    int t = (int)threadIdx.x;
    int wave = t >> 6, lane = t & 63;
    int mbase = blockIdx.x * 64 + wave * 16;
    int arow  = mbase + (lane & 15);
    if (arow >= N) arow = N - 1;             // clamped duplicate reads
    int kgrp  = lane >> 4;                   // 0..3

    // A-frag: lane holds X[arow][kt*32 + kgrp*8 .. +8], converted to fp16
    f16x8 afrag[4];
#pragma unroll
    for (int kt = 0; kt < 4; ++kt) {
        const float* xp = X + (size_t)arow * D + kt * 32 + kgrp * 8;
        float4 a0 = *(const float4*)xp;
        float4 a1 = *(const float4*)(xp + 4);
        f16x8 af;
        af[0] = (_Float16)a0.x; af[1] = (_Float16)a0.y;
        af[2] = (_Float16)a0.z; af[3] = (_Float16)a0.w;
        af[4] = (_Float16)a1.x; af[5] = (_Float16)a1.y;
        af[6] = (_Float16)a1.z; af[7] = (_Float16)a1.w;
        afrag[kt] = af;
    }
    f32x4 acc[8];
#pragma unroll
    for (int nt = 0; nt < 8; ++nt) acc[nt] = (f32x4){0.f, 0.f, 0.f, 0.f};
#pragma unroll
    for (int kt = 0; kt < 4; ++kt) {
#pragma unroll
        for (int nt = 0; nt < 8; ++nt) {
            uint4 u = *(const uint4*)(WB + (((kt * 8 + nt) * 64 + lane) * 8));
            f16x8 bfrag = __builtin_bit_cast(f16x8, u);
            acc[nt] = __builtin_amdgcn_mfma_f32_16x16x32_f16(afrag[kt], bfrag, acc[nt], 0, 0, 0);
        }
    }
    // C/D: col = lane&15, row = kgrp*4 + reg   [m89-verified, dtype-indep]
    int r0 = mbase + kgrp * 4;
#pragma unroll
    for (int r = 0; r < 4; ++r) {
        int row = r0 + r;
        if (row < N) {
            float dv = dinv[row];
#pragma unroll
            for (int nt = 0; nt < 8; ++nt) {
                size_t adr = ((size_t)(nt >> 1) * N + row) * 32 + (nt & 1) * 16 + (lane & 15);
                Gp[adr] = (_Float16)(dv * acc[nt][r]);
            }
        }
    }
}

// --- agg1: H''_i = dinv_i * relu(dinv_i*(sum_e G'_s + G'_i) + b1), fp16 -----
// Panel-pinned: panel = blockIdx&3 (round-robin bid->XCD keeps each XCD on
// one panel -> 3.2MB working set, L2-resident). Wave = 4 edge-slots (eq) x
// 16 col-lanes (cl, 2 fp16 cols each); 64B (one line) gathered per edge.
__global__ __launch_bounds__(256) void agg1_kernel(const unsigned* __restrict__ Gp,
                                                   const int* __restrict__ rowstart,
                                                   const unsigned short* __restrict__ colidx,
                                                   const float* __restrict__ dinv,
                                                   const float* __restrict__ b1,
                                                   unsigned* __restrict__ Hp,
                                                   int N, int chunk) {
    int bid  = (int)blockIdx.x;
    int p    = bid & (NPAN - 1);
    int gid  = (bid >> 2) * 4 + ((int)threadIdx.x >> 6);
    int lane = (int)threadIdx.x & 63;
    int eq   = lane >> 4;         // edge slot 0..3
    int cl   = lane & 15;         // 2 fp16 cols per lane
    const unsigned* P = Gp + (size_t)p * N * 16;
    unsigned*       H = Hp + (size_t)p * N * 16;
    float bx = b1[p * 32 + 2 * cl], by = b1[p * 32 + 2 * cl + 1];
    int i0 = gid * chunk, i1 = min(i0 + chunk, N);
    for (int i = i0; i < i1; ++i) {
        float di = dinv[i];
        float2 acc = make_float2(0.f, 0.f);
        if (eq == 0) {                              // self term
            float2 v = h2f(P[(size_t)i * 16 + cl]);
            acc.x = v.x; acc.y = v.y;
        }
        int e0 = rowstart[i], e1 = rowstart[i + 1];
        int e = e0;
        for (; e + 7 < e1; e += 8) {                // 8 edges, 2 gathers
            int c0 = (int)__builtin_nontemporal_load(&colidx[e + eq]);
            int c1 = (int)__builtin_nontemporal_load(&colidx[e + 4 + eq]);
            unsigned u0 = P[(size_t)c0 * 16 + cl];
            unsigned u1 = P[(size_t)c1 * 16 + cl];
            float2 v0 = h2f(u0), v1 = h2f(u1);
            acc.x += v0.x + v1.x;
            acc.y += v0.y + v1.y;
        }
        if (e + 3 < e1) {
            int c = (int)__builtin_nontemporal_load(&colidx[e + eq]);
            float2 v = h2f(P[(size_t)c * 16 + cl]);
            acc.x += v.x; acc.y += v.y;
            e += 4;
        }
        int rem = e1 - e;                           // 0..3 tail edges
        if (eq < rem) {
            int c = (int)__builtin_nontemporal_load(&colidx[e + eq]);
            float2 v = h2f(P[(size_t)c * 16 + cl]);
            acc.x += v.x; acc.y += v.y;
        }
        // reduce the 4 edge-slot groups (same cl)
        acc.x += __shfl_xor(acc.x, 16);
        acc.x += __shfl_xor(acc.x, 32);
        acc.y += __shfl_xor(acc.y, 16);
        acc.y += __shfl_xor(acc.y, 32);
        if (eq == 0) {
            float hx = fmaxf(fmaf(di, acc.x, bx), 0.f) * di;
            float hy = fmaxf(fmaf(di, acc.y, by), 0.f) * di;
            H[(size_t)i * 16 + cl] = f2h(hx, hy);
        }
    }
}

// --- agg2 + pool: pool[batch_i] += dinv_i*(sum_e H''_s + H''_i) -------------
__global__ __launch_bounds__(256) void agg2_pool_kernel(const unsigned* __restrict__ Hp,
                                                        const int* __restrict__ rowstart,
                                                        const unsigned short* __restrict__ colidx,
                                                        const float* __restrict__ dinv,
                                                        const int* __restrict__ batch,
                                                        float* __restrict__ pool,
                                                        int N, int chunk) {
    int bid  = (int)blockIdx.x;
    int p    = bid & (NPAN - 1);
    int gid  = (bid >> 2) * 4 + ((int)threadIdx.x >> 6);
    int lane = (int)threadIdx.x & 63;
    int eq   = lane >> 4;
    int cl   = lane & 15;
    const unsigned* P = Hp + (size_t)p * N * 16;
    int i0 = gid * chunk, i1 = min(i0 + chunk, N);
    if (i0 >= N) return;

    float2 pa = make_float2(0.f, 0.f);
    int cur = min(max(batch[i0], 0), NGRAPH - 1);
    for (int i = i0; i < i1; ++i) {
        float di = dinv[i];
        float2 acc = make_float2(0.f, 0.f);
        if (eq == 0) {                              // self term
            float2 v = h2f(P[(size_t)i * 16 + cl]);
            acc.x = v.x; acc.y = v.y;
        }
        int e0 = rowstart[i], e1 = rowstart[i + 1];
        int e = e0;
        for (; e + 7 < e1; e += 8) {
            int c0 = (int)__builtin_nontemporal_load(&colidx[e + eq]);
            int c1 = (int)__builtin_nontemporal_load(&colidx[e + 4 + eq]);
            unsigned u0 = P[(size_t)c0 * 16 + cl];
            unsigned u1 = P[(size_t)c1 * 16 + cl];
            float2 v0 = h2f(u0), v1 = h2f(u1);
            acc.x += v0.x + v1.x;
            acc.y += v0.y + v1.y;
        }
        if (e + 3 < e1) {
            int c = (int)__builtin_nontemporal_load(&colidx[e + eq]);
            float2 v = h2f(P[(size_t)c * 16 + cl]);
            acc.x += v.x; acc.y += v.y;
            e += 4;
        }
        int rem = e1 - e;
        if (eq < rem) {
            int c = (int)__builtin_nontemporal_load(&colidx[e + eq]);
            float2 v = h2f(P[(size_t)c * 16 + cl]);
            acc.x += v.x; acc.y += v.y;
        }
        acc.x += __shfl_xor(acc.x, 16);
        acc.x += __shfl_xor(acc.x, 32);
        acc.y += __shfl_xor(acc.y, 16);
        acc.y += __shfl_xor(acc.y, 32);

        int b = min(max(batch[i], 0), NGRAPH - 1);
        if (b != cur) {                             // uniform across wave
            if (eq == 0) {
                atomicAdd(&pool[(size_t)cur * D + p * 32 + 2 * cl],     pa.x);
                atomicAdd(&pool[(size_t)cur * D + p * 32 + 2 * cl + 1], pa.y);
            }
            pa = make_float2(0.f, 0.f);
            cur = b;
        }
        pa.x = fmaf(di, acc.x, pa.x);
        pa.y = fmaf(di, acc.y, pa.y);
    }
    if (eq == 0) {
        atomicAdd(&pool[(size_t)cur * D + p * 32 + 2 * cl],     pa.x);
        atomicAdd(&pool[(size_t)cur * D + p * 32 + 2 * cl + 1], pa.y);
    }
}

// --- Final tiny GEMM: out[g][o] = (pool[g]/cnt_g) . W2[:,o] + b2[o] ---------
__device__ __forceinline__ int lbound(const int* __restrict__ a, int n, int v) {
    int lo = 0, hi = n;
    while (lo < hi) {
        int m = (lo + hi) >> 1;
        if (a[m] < v) lo = m + 1; else hi = m;
    }
    return lo;
}

__global__ void final_gemm_kernel(const float* __restrict__ pool,
                                  const int* __restrict__ batch,
                                  const float* __restrict__ W2,
                                  const float* __restrict__ b2,
                                  float* __restrict__ out, int N) {
    int g = blockIdx.x, o = threadIdx.x;
    int s = lbound(batch, N, g);
    int e = lbound(batch, N, g + 1);
    float inv_cnt = 1.0f / fmaxf((float)(e - s), 1.0f);
    float acc = 0.f;
#pragma unroll 4
    for (int k = 0; k < D; ++k)
        acc = fmaf(pool[g * D + k], W2[k * D + o], acc);
    out[g * D + o] = acc * inv_cnt + b2[o];
}

// ---------------------------------------------------------------------------

extern "C" void kernel_launch(void* const* d_in, const int* in_sizes, int n_in,
                              void* d_out, int out_size, void* d_ws, size_t ws_size,
                              hipStream_t stream) {
    const float* x     = (const float*)d_in[0];
    const int*   ei    = (const int*)  d_in[1];
    const int*   batch = (const int*)  d_in[2];
    const float* W1    = (const float*)d_in[3];
    const float* b1    = (const float*)d_in[4];
    const float* W2    = (const float*)d_in[5];
    const float* b2    = (const float*)d_in[6];
    float* out = (float*)d_out;

    const int N = in_sizes[0] / D;
    const int E = in_sizes[1] / 2;
    const int nblk = (N + SCAN_B - 1) / SCAN_B;   // <=64 for N<=65536

    // workspace carve-up (256B aligned); deg+pool adjacent -> single memset
    char* ws = (char*)d_ws;
    size_t off = 0;
    auto carve = [&](size_t bytes) {
        size_t o = off;
        off = (off + bytes + 255) & ~(size_t)255;
        return o;
    };
    size_t o_deg      = carve((size_t)N * 4);
    size_t o_pool     = carve((size_t)NGRAPH * D * 4);
    size_t zspan      = off;                       // memset [0, zspan)
    size_t o_rowstart = carve((size_t)(N + 1) * 4);
    size_t o_cursor   = carve((size_t)(N + 1) * 4);
    size_t o_dinv     = carve((size_t)N * 4);
    size_t o_colidx   = carve((size_t)E * 2);      // ushort (N < 65536)
    size_t o_bsum     = carve((size_t)64 * 4);
    size_t o_wb       = carve((size_t)D * D * 2);  // fp16 W1 (MFMA B order)
    size_t o_gh       = carve((size_t)N * D * 2);  // fp16 G' (panel-major)
    size_t o_hh       = carve((size_t)N * D * 2);  // fp16 H'' (panel-major)
    size_t need = off;

    if (ws_size < need) {
        zero_out_kernel<<<(out_size + 255) / 256, 256, 0, stream>>>(out, out_size);
        return;
    }

    int*            deg      = (int*)           (ws + o_deg);
    float*          pool     = (float*)         (ws + o_pool);
    int*            rowstart = (int*)           (ws + o_rowstart);
    int*            cursor   = (int*)           (ws + o_cursor);
    float*          dinv     = (float*)         (ws + o_dinv);
    unsigned short* colidx   = (unsigned short*)(ws + o_colidx);
    int*            bsum     = (int*)           (ws + o_bsum);
    _Float16*       WB       = (_Float16*)      (ws + o_wb);
    _Float16*       Gh       = (_Float16*)      (ws + o_gh);
    _Float16*       Hh       = (_Float16*)      (ws + o_hh);

    hipMemsetAsync(ws, 0, zspan, stream);          // deg + pool in one shot

    int eb = (E + 255) / 256;
    int gb = (N + 63) / 64;

    pack_count_kernel<<<8 + eb, 256, 0, stream>>>(W1, WB, ei, deg, N, E);
    block_scan_kernel<<<nblk, SCAN_B, 0, stream>>>(deg, rowstart, bsum, dinv, N);
    finalize_scan_kernel<<<nblk, SCAN_B, 0, stream>>>(bsum, rowstart, cursor, N, nblk, E);
    gemm_fill_kernel<<<gb + eb, 256, 0, stream>>>(x, WB, dinv, Gh, ei, cursor,
                                                  colidx, N, E, gb);

    // waves(groups) per panel = (AGG_BLOCKS/NPAN)*4 = AGG_BLOCKS
    int chunk = (N + AGG_BLOCKS - 1) / AGG_BLOCKS;
    agg1_kernel<<<AGG_BLOCKS, 256, 0, stream>>>((const unsigned*)Gh, rowstart, colidx,
                                                dinv, b1, (unsigned*)Hh, N, chunk);
    agg2_pool_kernel<<<AGG_BLOCKS, 256, 0, stream>>>((const unsigned*)Hh, rowstart, colidx,
                                                     dinv, batch, pool, N, chunk);
    final_gemm_kernel<<<NGRAPH, D, 0, stream>>>(pool, batch, W2, b2, out, N);
}

// Round 3
// 225.573 us; speedup vs baseline: 1.4318x; 1.4318x over previous
//
#include <hip/hip_runtime.h>

// ---------------------------------------------------------------------------
// 2-layer GCN + global mean pool, MI355X (gfx950).
//   A_hat = D^{-1/2}(A+I)D^{-1/2}
//   G' = dinv*(X @ W1) fp16 [MFMA fp16];  H'' = dinv*relu(dinv*A_sum(G')+b1)
//   out = pool(dinv*A_sum(H'')) @ W2 + b2
// R13: latency-bound fixes (R12 post-mortem: device-scope atomics are
//   LLC-level RMWs -> 41MB WRITE_SIZE; aggs latency-bound not BW-bound).
//   (1) count & fill unroll 4 edges/thread -> 4x in-flight atomics.
//   (2) CSR rows padded to multiple of 8 with sentinel row N (zeroed):
//       agg inner loop is branchless uniform 8-deep gather bursts; colidx
//       (ushort) loaded as one 16B vector per burst. Full-row-per-edge
//       gather (R10 structure, best measured).
// ws_size is 256 MiB; we use ~29 MB.
// ---------------------------------------------------------------------------

#define D 128
#define NGRAPH 64
#define SCAN_B 1024
#define AGG_BLOCKS 2048   // 8192 waves = 32/CU

typedef _Float16 h16x2 __attribute__((ext_vector_type(2)));
typedef _Float16 f16x8 __attribute__((ext_vector_type(8)));
typedef float    f32x4 __attribute__((ext_vector_type(4)));
typedef unsigned short u16x8 __attribute__((ext_vector_type(8)));

__device__ __forceinline__ float2 h2f(unsigned u) {
    h16x2 h = __builtin_bit_cast(h16x2, u);
    return make_float2((float)h.x, (float)h.y);
}
__device__ __forceinline__ unsigned f2h(float x, float y) {
    h16x2 h;
    h.x = (_Float16)x;
    h.y = (_Float16)y;
    return __builtin_bit_cast(unsigned, h);
}

// --- diagnostic: all-zero output (ws too small) ----------------------------
__global__ void zero_out_kernel(float* __restrict__ out, int n) {
    int i = blockIdx.x * blockDim.x + threadIdx.x;
    if (i < n) out[i] = 0.f;
}

// --- Fused: W1->fp16 MFMA-B pack | zero sentinel rows | degree count -------
// Blocks [0,8): pack WB. Block 8: zero Gh[N], Hh[N] (sentinel rows).
// Blocks [9, 9+ebc): count dst degrees, 4 edges/thread (4 in-flight atomics).
__global__ __launch_bounds__(256) void pack_count_kernel(const float* __restrict__ W1,
                                                         _Float16* __restrict__ WB,
                                                         const int* __restrict__ ei,
                                                         int* __restrict__ deg,
                                                         unsigned* __restrict__ Gz,
                                                         unsigned* __restrict__ Hz,
                                                         int N, int E) {
    int b = (int)blockIdx.x;
    if (b < 8) {
        // WB[((kt*8+nt)*64+lane)*8+j] = W1[(kt*32+(lane>>4)*8+j)*D + nt*16+(lane&15)]
        int idx = b * 256 + (int)threadIdx.x;          // 0..2047
        int lane = idx & 63;
        int nt   = (idx >> 6) & 7;
        int kt   = idx >> 9;
        int col  = nt * 16 + (lane & 15);
        int krow = kt * 32 + (lane >> 4) * 8;
#pragma unroll
        for (int j = 0; j < 8; ++j)
            WB[idx * 8 + j] = (_Float16)W1[(krow + j) * D + col];
        return;
    }
    if (b == 8) {
        int t = (int)threadIdx.x;
        if (t < 64)       Gz[(size_t)N * 64 + t] = 0u;          // Gh row N = 0
        else if (t < 128) Hz[(size_t)N * 64 + (t - 64)] = 0u;   // Hh row N = 0
        return;
    }
    int e0 = (b - 9) * 1024 + (int)threadIdx.x;
    int d[4];
#pragma unroll
    for (int j = 0; j < 4; ++j) {
        int e = e0 + j * 256;
        d[j] = (e < E) ? ei[E + e] : -1;
    }
#pragma unroll
    for (int j = 0; j < 4; ++j)
        if (d[j] >= 0 && d[j] < N) atomicAdd(&deg[d[j]], 1);
}

// per-block scan of PADDED deg (round up to 8) -> local exclusive prefix;
// also emits dinv from TRUE degree.
__global__ __launch_bounds__(SCAN_B) void block_scan_kernel(const int* __restrict__ deg,
                                                            int* __restrict__ rowstart,
                                                            int* __restrict__ bsum,
                                                            float* __restrict__ dinv,
                                                            int N) {
    __shared__ int sc[SCAN_B];
    int t = threadIdx.x;
    int i = blockIdx.x * SCAN_B + t;
    int orig = (i < N) ? deg[i] : 0;
    int pad8 = (orig + 7) & ~7;
    int v = pad8;
    sc[t] = v;
    __syncthreads();
    for (int off = 1; off < SCAN_B; off <<= 1) {
        int add = (t >= off) ? sc[t - off] : 0;
        __syncthreads();
        v += add;
        sc[t] = v;
        __syncthreads();
    }
    if (i < N) {
        rowstart[i] = v - pad8;                      // local exclusive (padded)
        dinv[i]     = rsqrtf((float)orig + 1.0f);    // +1 self loop (true deg)
    }
    if (t == SCAN_B - 1) bsum[blockIdx.x] = v;
}

// each block self-computes its bsum prefix (nblk<=64); writes rowstart/cursor,
// fills pad slots [rs+deg, rs+pad8) with sentinel N, and rowstart[N]=total.
__global__ __launch_bounds__(SCAN_B) void finalize_scan_kernel(const int* __restrict__ bsum,
                                                               const int* __restrict__ deg,
                                                               int* __restrict__ rowstart,
                                                               int* __restrict__ cursor,
                                                               unsigned short* __restrict__ colidx,
                                                               int N, int nblk) {
    __shared__ int s_off;
    if (threadIdx.x < 64) {
        int lane = (int)threadIdx.x;
        int bv = (lane < nblk) ? bsum[lane] : 0;
        int v  = (lane < (int)blockIdx.x) ? bv : 0;
        int vt = bv;
        for (int off = 32; off > 0; off >>= 1) {
            v  += __shfl_down(v, off);
            vt += __shfl_down(vt, off);
        }
        if (lane == 0) {
            s_off = v;
            if (blockIdx.x == 0) rowstart[N] = vt;   // padded total
        }
    }
    __syncthreads();
    int i = blockIdx.x * SCAN_B + threadIdx.x;
    if (i < N) {
        int rs = rowstart[i] + s_off;
        rowstart[i] = rs;
        cursor[i]   = rs;
        int dg = deg[i];
        int p8 = (dg + 7) & ~7;
        for (int k = dg; k < p8; ++k)
            colidx[rs + k] = (unsigned short)N;      // sentinel -> zero row
    }
}

// --- Fused MFMA GEMM + fill -------------------------------------------------
// Blocks [0,gb): G' = dinv*(X @ W1h) via mfma_f32_16x16x32_f16, fp16 out.
//   A-frag converted fp32->fp16 in-register (no staging pass).
// Blocks [gb,gb+ebf): CSR fill, 4 edges/thread (4 in-flight cursor atomics).
__global__ __launch_bounds__(256) void gemm_fill_kernel(const float* __restrict__ X,
                                                        const _Float16* __restrict__ WB,
                                                        const float* __restrict__ dinv,
                                                        _Float16* __restrict__ Gh,
                                                        const int* __restrict__ ei,
                                                        int* __restrict__ cursor,
                                                        unsigned short* __restrict__ colidx,
                                                        int N, int E, int gb) {
    if ((int)blockIdx.x >= gb) {
        int e0 = ((int)blockIdx.x - gb) * 1024 + (int)threadIdx.x;
        int d[4], s[4], slot[4];
#pragma unroll
        for (int j = 0; j < 4; ++j) {
            int e = e0 + j * 256;
            if (e < E) {
                d[j] = ei[E + e];
                s[j] = ei[e];
            } else d[j] = -1;
        }
#pragma unroll
        for (int j = 0; j < 4; ++j)
            if (d[j] >= 0 && d[j] < N) slot[j] = atomicAdd(&cursor[d[j]], 1);
#pragma unroll
        for (int j = 0; j < 4; ++j)
            if (d[j] >= 0 && d[j] < N)
                colidx[slot[j]] = (unsigned short)min(max(s[j], 0), N - 1);
        return;
    }

    int t = (int)threadIdx.x;
    int wave = t >> 6, lane = t & 63;
    int mbase = blockIdx.x * 64 + wave * 16;
    int arow  = mbase + (lane & 15);
    if (arow >= N) arow = N - 1;             // clamped duplicate reads
    int kgrp  = lane >> 4;                   // 0..3

    // A-frag: lane holds X[arow][kt*32 + kgrp*8 .. +8], converted to fp16
    f16x8 afrag[4];
#pragma unroll
    for (int kt = 0; kt < 4; ++kt) {
        const float* xp = X + (size_t)arow * D + kt * 32 + kgrp * 8;
        float4 a0 = *(const float4*)xp;
        float4 a1 = *(const float4*)(xp + 4);
        f16x8 af;
        af[0] = (_Float16)a0.x; af[1] = (_Float16)a0.y;
        af[2] = (_Float16)a0.z; af[3] = (_Float16)a0.w;
        af[4] = (_Float16)a1.x; af[5] = (_Float16)a1.y;
        af[6] = (_Float16)a1.z; af[7] = (_Float16)a1.w;
        afrag[kt] = af;
    }
    f32x4 acc[8];
#pragma unroll
    for (int nt = 0; nt < 8; ++nt) acc[nt] = (f32x4){0.f, 0.f, 0.f, 0.f};
#pragma unroll
    for (int kt = 0; kt < 4; ++kt) {
#pragma unroll
        for (int nt = 0; nt < 8; ++nt) {
            uint4 u = *(const uint4*)(WB + (((kt * 8 + nt) * 64 + lane) * 8));
            f16x8 bfrag = __builtin_bit_cast(f16x8, u);
            acc[nt] = __builtin_amdgcn_mfma_f32_16x16x32_f16(afrag[kt], bfrag, acc[nt], 0, 0, 0);
        }
    }
    // C/D: col = lane&15, row = kgrp*4 + reg   [m89-verified, dtype-indep]
    int r0 = mbase + kgrp * 4;
#pragma unroll
    for (int r = 0; r < 4; ++r) {
        int row = r0 + r;
        if (row < N) {
            float dv = dinv[row];
#pragma unroll
            for (int nt = 0; nt < 8; ++nt)
                Gh[(size_t)row * D + nt * 16 + (lane & 15)] = (_Float16)(dv * acc[nt][r]);
        }
    }
}

// --- agg1: H''_i = dinv_i * relu(dinv_i*(sum_e G'_s + G'_i) + b1), fp16 -----
// 64-lane wave per node; padded CSR -> branchless 8-deep gather bursts.
__global__ __launch_bounds__(256) void agg1_kernel(const unsigned* __restrict__ Gh,
                                                   const int* __restrict__ rowstart,
                                                   const unsigned short* __restrict__ colidx,
                                                   const float* __restrict__ dinv,
                                                   const float* __restrict__ b1,
                                                   unsigned* __restrict__ Hh,
                                                   int N, int chunk) {
    int gid  = blockIdx.x * 4 + (threadIdx.x >> 6);
    int lane = threadIdx.x & 63;
    int i0 = gid * chunk, i1 = min(i0 + chunk, N);
    float bx = b1[2 * lane], by = b1[2 * lane + 1];
    for (int i = i0; i < i1; ++i) {
        float di = dinv[i];
        float2 acc = h2f(Gh[(size_t)i * 64 + lane]);        // self term
        int e0 = rowstart[i], e1 = rowstart[i + 1];         // both mult of 8
        for (int e = e0; e < e1; e += 8) {
            u16x8 cc = *(const u16x8*)(colidx + e);         // 16B, aligned
            unsigned u[8];
#pragma unroll
            for (int j = 0; j < 8; ++j)
                u[j] = Gh[(size_t)cc[j] * 64 + lane];
#pragma unroll
            for (int j = 0; j < 8; ++j) {
                float2 v = h2f(u[j]);
                acc.x += v.x;
                acc.y += v.y;
            }
        }
        float hx = fmaxf(fmaf(di, acc.x, bx), 0.f) * di;    // H'' = dinv*relu
        float hy = fmaxf(fmaf(di, acc.y, by), 0.f) * di;
        Hh[(size_t)i * 64 + lane] = f2h(hx, hy);
    }
}

// --- agg2 + pool: pool[batch_i] += dinv_i*(sum_e H''_s + H''_i) -------------
__global__ __launch_bounds__(256) void agg2_pool_kernel(const unsigned* __restrict__ Hh,
                                                        const int* __restrict__ rowstart,
                                                        const unsigned short* __restrict__ colidx,
                                                        const float* __restrict__ dinv,
                                                        const int* __restrict__ batch,
                                                        float* __restrict__ pool,
                                                        int N, int chunk) {
    int gid  = blockIdx.x * 4 + (threadIdx.x >> 6);
    int lane = threadIdx.x & 63;
    int i0 = gid * chunk, i1 = min(i0 + chunk, N);
    if (i0 >= N) return;

    float2 pa = make_float2(0.f, 0.f);
    int cur = min(max(batch[i0], 0), NGRAPH - 1);
    for (int i = i0; i < i1; ++i) {
        float di = dinv[i];
        float2 a = h2f(Hh[(size_t)i * 64 + lane]);          // self term
        int e0 = rowstart[i], e1 = rowstart[i + 1];
        for (int e = e0; e < e1; e += 8) {
            u16x8 cc = *(const u16x8*)(colidx + e);
            unsigned u[8];
#pragma unroll
            for (int j = 0; j < 8; ++j)
                u[j] = Hh[(size_t)cc[j] * 64 + lane];
#pragma unroll
            for (int j = 0; j < 8; ++j) {
                float2 v = h2f(u[j]);
                a.x += v.x;
                a.y += v.y;
            }
        }
        int b = min(max(batch[i], 0), NGRAPH - 1);
        if (b != cur) {                                     // uniform per wave
            atomicAdd(&pool[(size_t)cur * D + 2 * lane], pa.x);
            atomicAdd(&pool[(size_t)cur * D + 2 * lane + 1], pa.y);
            pa = make_float2(0.f, 0.f);
            cur = b;
        }
        pa.x = fmaf(di, a.x, pa.x);
        pa.y = fmaf(di, a.y, pa.y);
    }
    atomicAdd(&pool[(size_t)cur * D + 2 * lane], pa.x);
    atomicAdd(&pool[(size_t)cur * D + 2 * lane + 1], pa.y);
}

// --- Final tiny GEMM: out[g][o] = (pool[g]/cnt_g) . W2[:,o] + b2[o] ---------
__device__ __forceinline__ int lbound(const int* __restrict__ a, int n, int v) {
    int lo = 0, hi = n;
    while (lo < hi) {
        int m = (lo + hi) >> 1;
        if (a[m] < v) lo = m + 1; else hi = m;
    }
    return lo;
}

__global__ void final_gemm_kernel(const float* __restrict__ pool,
                                  const int* __restrict__ batch,
                                  const float* __restrict__ W2,
                                  const float* __restrict__ b2,
                                  float* __restrict__ out, int N) {
    int g = blockIdx.x, o = threadIdx.x;
    int s = lbound(batch, N, g);
    int e = lbound(batch, N, g + 1);
    float inv_cnt = 1.0f / fmaxf((float)(e - s), 1.0f);
    float acc = 0.f;
#pragma unroll 4
    for (int k = 0; k < D; ++k)
        acc = fmaf(pool[g * D + k], W2[k * D + o], acc);
    out[g * D + o] = acc * inv_cnt + b2[o];
}

// ---------------------------------------------------------------------------

extern "C" void kernel_launch(void* const* d_in, const int* in_sizes, int n_in,
                              void* d_out, int out_size, void* d_ws, size_t ws_size,
                              hipStream_t stream) {
    const float* x     = (const float*)d_in[0];
    const int*   ei    = (const int*)  d_in[1];
    const int*   batch = (const int*)  d_in[2];
    const float* W1    = (const float*)d_in[3];
    const float* b1    = (const float*)d_in[4];
    const float* W2    = (const float*)d_in[5];
    const float* b2    = (const float*)d_in[6];
    float* out = (float*)d_out;

    const int N = in_sizes[0] / D;
    const int E = in_sizes[1] / 2;
    const int nblk = (N + SCAN_B - 1) / SCAN_B;   // <=64 for N<=65536

    // workspace carve-up (256B aligned); deg+pool adjacent -> single memset
    char* ws = (char*)d_ws;
    size_t off = 0;
    auto carve = [&](size_t bytes) {
        size_t o = off;
        off = (off + bytes + 255) & ~(size_t)255;
        return o;
    };
    size_t o_deg      = carve((size_t)N * 4);
    size_t o_pool     = carve((size_t)NGRAPH * D * 4);
    size_t zspan      = off;                       // memset [0, zspan)
    size_t o_rowstart = carve((size_t)(N + 1) * 4);
    size_t o_cursor   = carve((size_t)(N + 1) * 4);
    size_t o_dinv     = carve((size_t)N * 4);
    size_t o_colidx   = carve(((size_t)E + 7 * (size_t)N + 64) * 2);  // padded
    size_t o_bsum     = carve((size_t)64 * 4);
    size_t o_wb       = carve((size_t)D * D * 2);        // fp16 W1 (MFMA B)
    size_t o_gh       = carve((size_t)(N + 1) * D * 2);  // fp16 G' (+zero row)
    size_t o_hh       = carve((size_t)(N + 1) * D * 2);  // fp16 H'' (+zero row)
    size_t need = off;

    if (ws_size < need) {
        zero_out_kernel<<<(out_size + 255) / 256, 256, 0, stream>>>(out, out_size);
        return;
    }

    int*            deg      = (int*)           (ws + o_deg);
    float*          pool     = (float*)         (ws + o_pool);
    int*            rowstart = (int*)           (ws + o_rowstart);
    int*            cursor   = (int*)           (ws + o_cursor);
    float*          dinv     = (float*)         (ws + o_dinv);
    unsigned short* colidx   = (unsigned short*)(ws + o_colidx);
    int*            bsum     = (int*)           (ws + o_bsum);
    _Float16*       WB       = (_Float16*)      (ws + o_wb);
    _Float16*       Gh       = (_Float16*)      (ws + o_gh);
    _Float16*       Hh       = (_Float16*)      (ws + o_hh);

    hipMemsetAsync(ws, 0, zspan, stream);          // deg + pool in one shot

    int ebc = (E + 1023) / 1024;                   // count/fill: 4 edges/thread
    int gb  = (N + 63) / 64;

    pack_count_kernel<<<9 + ebc, 256, 0, stream>>>(W1, WB, ei, deg,
                                                   (unsigned*)Gh, (unsigned*)Hh, N, E);
    block_scan_kernel<<<nblk, SCAN_B, 0, stream>>>(deg, rowstart, bsum, dinv, N);
    finalize_scan_kernel<<<nblk, SCAN_B, 0, stream>>>(bsum, deg, rowstart, cursor,
                                                      colidx, N, nblk);
    gemm_fill_kernel<<<gb + ebc, 256, 0, stream>>>(x, WB, dinv, Gh, ei, cursor,
                                                   colidx, N, E, gb);

    int groups = AGG_BLOCKS * 4;
    int chunk  = (N + groups - 1) / groups;
    agg1_kernel<<<AGG_BLOCKS, 256, 0, stream>>>((const unsigned*)Gh, rowstart, colidx,
                                                dinv, b1, (unsigned*)Hh, N, chunk);
    agg2_pool_kernel<<<AGG_BLOCKS, 256, 0, stream>>>((const unsigned*)Hh, rowstart, colidx,
                                                     dinv, batch, pool, N, chunk);
    final_gemm_kernel<<<NGRAPH, D, 0, stream>>>(pool, batch, W2, b2, out, N);
}

// Round 4
// 196.434 us; speedup vs baseline: 1.6442x; 1.1483x over previous
//
#include <hip/hip_runtime.h>

// ---------------------------------------------------------------------------
// 2-layer GCN + global mean pool, MI355X (gfx950).
//   A_hat = D^{-1/2}(A+I)D^{-1/2}
//   G' = dinv*(X @ W1) fp16 [MFMA fp16];  H'' = dinv*relu(dinv*A_sum(G')+b1)
//   out = pool(dinv*A_sum(H'')) @ W2 + b2
// R14: CSR build WITHOUT per-edge global atomics (R13 post-mortem: 1.28M
//   device-scope atomics = LLC-level RMWs, ~41MB phantom WRITE_SIZE, ~70us).
//   Two-level counting sort:
//     K1: 1024-edge blocks -> LDS histogram over 128 dst-buckets (d>>9),
//         reserve spans with 128 global atomics/BLOCK (80K total, was 640K),
//         scatter packed (d<<16|s) into bucket arrays.
//     K2: per-bucket degree count via LDS atomics; emits deg/dinv/padsum.
//     K3: 1-block scan of bucket padded sums -> bucket bases, rowstart[N].
//     K4 (fused with MFMA GEMM): per-bucket LDS scan -> rowstart, sentinel
//         pads, colidx fill via LDS cursors. Zero global atomics.
//   Aggs: R13 structure unchanged (padded branchless 8-deep bursts).
// ws_size is 256 MiB; we use ~35 MB.
// ---------------------------------------------------------------------------

#define D 128
#define NGRAPH 64
#define AGG_BLOCKS 2048   // 8192 waves = 32/CU
#define BUCK_SH 9         // bucket = dst >> 9 (width 512)
#define BUCK_W  512
#define MAXBUCK 128       // N <= 65536

typedef _Float16 h16x2 __attribute__((ext_vector_type(2)));
typedef _Float16 f16x8 __attribute__((ext_vector_type(8)));
typedef float    f32x4 __attribute__((ext_vector_type(4)));
typedef unsigned short u16x8 __attribute__((ext_vector_type(8)));

__device__ __forceinline__ float2 h2f(unsigned u) {
    h16x2 h = __builtin_bit_cast(h16x2, u);
    return make_float2((float)h.x, (float)h.y);
}
__device__ __forceinline__ unsigned f2h(float x, float y) {
    h16x2 h;
    h.x = (_Float16)x;
    h.y = (_Float16)y;
    return __builtin_bit_cast(unsigned, h);
}

// --- diagnostic: all-zero output (ws too small) ----------------------------
__global__ void zero_out_kernel(float* __restrict__ out, int n) {
    int i = blockIdx.x * blockDim.x + threadIdx.x;
    if (i < n) out[i] = 0.f;
}

// --- K1: W1 pack (blocks 0..7) | zero sentinel rows (block 8) | bucket
//     scatter (blocks 9..): LDS histogram + per-block span reservation. -----
__global__ __launch_bounds__(256) void pack_scatter_kernel(const float* __restrict__ W1,
                                                           _Float16* __restrict__ WB,
                                                           const int* __restrict__ ei,
                                                           int* __restrict__ bcnt,
                                                           unsigned* __restrict__ buck,
                                                           unsigned* __restrict__ Gz,
                                                           unsigned* __restrict__ Hz,
                                                           int N, int E, int CAP) {
    int b = (int)blockIdx.x;
    int t = (int)threadIdx.x;
    if (b < 8) {
        // WB[((kt*8+nt)*64+lane)*8+j] = W1[(kt*32+(lane>>4)*8+j)*D + nt*16+(lane&15)]
        int idx = b * 256 + t;                         // 0..2047
        int lane = idx & 63;
        int nt   = (idx >> 6) & 7;
        int kt   = idx >> 9;
        int col  = nt * 16 + (lane & 15);
        int krow = kt * 32 + (lane >> 4) * 8;
#pragma unroll
        for (int j = 0; j < 8; ++j)
            WB[idx * 8 + j] = (_Float16)W1[(krow + j) * D + col];
        return;
    }
    if (b == 8) {
        if (t < 64)       Gz[(size_t)N * 64 + t] = 0u;          // Gh row N = 0
        else if (t < 128) Hz[(size_t)N * 64 + (t - 64)] = 0u;   // Hh row N = 0
        return;
    }
    __shared__ unsigned histL[MAXBUCK];
    __shared__ int      baseL[MAXBUCK];
    if (t < MAXBUCK) histL[t] = 0u;
    __syncthreads();

    int e0 = (b - 9) * 1024;
    int bid[4];
    unsigned lidx[4], pk[4];
#pragma unroll
    for (int j = 0; j < 4; ++j) {
        int e = e0 + t + j * 256;
        bid[j] = -1;
        if (e < E) {
            int s = ei[e];
            int d = ei[E + e];
            if (d >= 0 && d < N) {
                s = min(max(s, 0), N - 1);
                bid[j] = d >> BUCK_SH;
                pk[j]  = ((unsigned)d << 16) | (unsigned)s;
            }
        }
    }
#pragma unroll
    for (int j = 0; j < 4; ++j)
        if (bid[j] >= 0) lidx[j] = atomicAdd(&histL[bid[j]], 1u);
    __syncthreads();
    if (t < MAXBUCK && histL[t] > 0u)
        baseL[t] = atomicAdd(&bcnt[t], (int)histL[t]);
    __syncthreads();
#pragma unroll
    for (int j = 0; j < 4; ++j)
        if (bid[j] >= 0) {
            int slot = baseL[bid[j]] + (int)lidx[j];
            if (slot < CAP) buck[(size_t)bid[j] * CAP + slot] = pk[j];
        }
}

// --- K2: per-bucket degree count (LDS atomics) -> deg, dinv, padded sum ----
__global__ __launch_bounds__(256) void bucket_deg_kernel(const unsigned* __restrict__ buck,
                                                         const int* __restrict__ bcnt,
                                                         int* __restrict__ deg,
                                                         float* __restrict__ dinv,
                                                         int* __restrict__ padsum,
                                                         int N, int CAP) {
    __shared__ int degL[BUCK_W];
    __shared__ int red[256];
    int b = (int)blockIdx.x;
    int t = (int)threadIdx.x;
    for (int k = t; k < BUCK_W; k += 256) degL[k] = 0;
    __syncthreads();
    int cnt = min(bcnt[b], CAP);
    const unsigned* bp = buck + (size_t)b * CAP;
    for (int i = t; i < cnt; i += 256)
        atomicAdd(&degL[(bp[i] >> 16) & (BUCK_W - 1)], 1);
    __syncthreads();
    int base = b << BUCK_SH;
    int local = 0;
    for (int k = t; k < BUCK_W; k += 256) {
        int d = base + k;
        if (d < N) {
            int dg = degL[k];
            deg[d]  = dg;
            dinv[d] = rsqrtf((float)dg + 1.0f);
            local  += (dg + 7) & ~7;
        }
    }
    red[t] = local;
    __syncthreads();
    for (int off = 128; off > 0; off >>= 1) {
        if (t < off) red[t] += red[t + off];
        __syncthreads();
    }
    if (t == 0) padsum[b] = red[0];
}

// --- K3: scan bucket padded sums -> bases; rowstart[N] = total -------------
__global__ __launch_bounds__(128) void bucket_scan_kernel(const int* __restrict__ padsum,
                                                          int* __restrict__ bbase,
                                                          int* __restrict__ rowstart,
                                                          int N, int nbuck) {
    __shared__ int s[128];
    int t = (int)threadIdx.x;
    int own = (t < nbuck) ? padsum[t] : 0;
    s[t] = own;
    __syncthreads();
    for (int off = 1; off < 128; off <<= 1) {
        int v = (t >= off) ? s[t - off] : 0;
        __syncthreads();
        s[t] += v;
        __syncthreads();
    }
    if (t < nbuck) bbase[t] = s[t] - own;            // exclusive
    if (t == 127) rowstart[N] = s[127];
}

// --- K4: fused MFMA GEMM (blocks [0,gb)) + bucket CSR fill ([gb,gb+nbuck)) -
// Fill: per-bucket LDS scan of padded degrees -> rowstart; sentinel pads;
// colidx placement via LDS cursors. Zero global atomics.
__global__ __launch_bounds__(256) void gemm_fill_kernel(const float* __restrict__ X,
                                                        const _Float16* __restrict__ WB,
                                                        const float* __restrict__ dinv,
                                                        _Float16* __restrict__ Gh,
                                                        const unsigned* __restrict__ buck,
                                                        const int* __restrict__ bcnt,
                                                        const int* __restrict__ deg,
                                                        const int* __restrict__ bbase,
                                                        int* __restrict__ rowstart,
                                                        unsigned short* __restrict__ colidx,
                                                        int N, int CAP, int gb) {
    if ((int)blockIdx.x >= gb) {
        __shared__ int degS[BUCK_W];    // deg, later absolute cursors
        __shared__ int loff[BUCK_W];
        __shared__ int sc[256];
        int b = (int)blockIdx.x - gb;
        int t = (int)threadIdx.x;
        int base_d = b << BUCK_SH;
        for (int k = t; k < BUCK_W; k += 256) {
            int d = base_d + k;
            degS[k] = (d < N) ? deg[d] : 0;
        }
        __syncthreads();
        // scan pad8 over 512 entries: thread t owns 2t, 2t+1
        int p0 = (degS[2 * t] + 7) & ~7;
        int p1 = (degS[2 * t + 1] + 7) & ~7;
        int own = p0 + p1;
        sc[t] = own;
        __syncthreads();
        for (int off = 1; off < 256; off <<= 1) {
            int v = (t >= off) ? sc[t - off] : 0;
            __syncthreads();
            sc[t] += v;
            __syncthreads();
        }
        int excl = sc[t] - own;
        loff[2 * t]     = excl;
        loff[2 * t + 1] = excl + p0;
        __syncthreads();
        int bb = bbase[b];
        // rowstart + sentinel pads (uses degS as degrees still)
        for (int k = t; k < BUCK_W; k += 256) {
            int d = base_d + k;
            if (d < N) {
                int rs = bb + loff[k];
                rowstart[d] = rs;
                int dg = degS[k];
                int p8 = (dg + 7) & ~7;
                for (int j = dg; j < p8; ++j)
                    colidx[rs + j] = (unsigned short)N;   // sentinel -> zero row
            }
        }
        __syncthreads();
        // convert degS -> absolute cursors
        for (int k = t; k < BUCK_W; k += 256) degS[k] = bb + loff[k];
        __syncthreads();
        int cnt = min(bcnt[b], CAP);
        const unsigned* bp = buck + (size_t)b * CAP;
        for (int i = t; i < cnt; i += 256) {
            unsigned u = bp[i];
            int ld = (int)((u >> 16) & (BUCK_W - 1));
            int slot = atomicAdd(&degS[ld], 1);           // LDS atomic
            colidx[slot] = (unsigned short)(u & 0xffffu);
        }
        return;
    }

    int t = (int)threadIdx.x;
    int wave = t >> 6, lane = t & 63;
    int mbase = blockIdx.x * 64 + wave * 16;
    int arow  = mbase + (lane & 15);
    if (arow >= N) arow = N - 1;             // clamped duplicate reads
    int kgrp  = lane >> 4;                   // 0..3

    // A-frag: lane holds X[arow][kt*32 + kgrp*8 .. +8], converted to fp16
    f16x8 afrag[4];
#pragma unroll
    for (int kt = 0; kt < 4; ++kt) {
        const float* xp = X + (size_t)arow * D + kt * 32 + kgrp * 8;
        float4 a0 = *(const float4*)xp;
        float4 a1 = *(const float4*)(xp + 4);
        f16x8 af;
        af[0] = (_Float16)a0.x; af[1] = (_Float16)a0.y;
        af[2] = (_Float16)a0.z; af[3] = (_Float16)a0.w;
        af[4] = (_Float16)a1.x; af[5] = (_Float16)a1.y;
        af[6] = (_Float16)a1.z; af[7] = (_Float16)a1.w;
        afrag[kt] = af;
    }
    f32x4 acc[8];
#pragma unroll
    for (int nt = 0; nt < 8; ++nt) acc[nt] = (f32x4){0.f, 0.f, 0.f, 0.f};
#pragma unroll
    for (int kt = 0; kt < 4; ++kt) {
#pragma unroll
        for (int nt = 0; nt < 8; ++nt) {
            uint4 u = *(const uint4*)(WB + (((kt * 8 + nt) * 64 + lane) * 8));
            f16x8 bfrag = __builtin_bit_cast(f16x8, u);
            acc[nt] = __builtin_amdgcn_mfma_f32_16x16x32_f16(afrag[kt], bfrag, acc[nt], 0, 0, 0);
        }
    }
    // C/D: col = lane&15, row = kgrp*4 + reg   [m89-verified, dtype-indep]
    int r0 = mbase + kgrp * 4;
#pragma unroll
    for (int r = 0; r < 4; ++r) {
        int row = r0 + r;
        if (row < N) {
            float dv = dinv[row];
#pragma unroll
            for (int nt = 0; nt < 8; ++nt)
                Gh[(size_t)row * D + nt * 16 + (lane & 15)] = (_Float16)(dv * acc[nt][r]);
        }
    }
}

// --- agg1: H''_i = dinv_i * relu(dinv_i*(sum_e G'_s + G'_i) + b1), fp16 -----
// 64-lane wave per node; padded CSR -> branchless 8-deep gather bursts.
__global__ __launch_bounds__(256) void agg1_kernel(const unsigned* __restrict__ Gh,
                                                   const int* __restrict__ rowstart,
                                                   const unsigned short* __restrict__ colidx,
                                                   const float* __restrict__ dinv,
                                                   const float* __restrict__ b1,
                                                   unsigned* __restrict__ Hh,
                                                   int N, int chunk) {
    int gid  = blockIdx.x * 4 + (threadIdx.x >> 6);
    int lane = threadIdx.x & 63;
    int i0 = gid * chunk, i1 = min(i0 + chunk, N);
    float bx = b1[2 * lane], by = b1[2 * lane + 1];
    for (int i = i0; i < i1; ++i) {
        float di = dinv[i];
        float2 acc = h2f(Gh[(size_t)i * 64 + lane]);        // self term
        int e0 = rowstart[i], e1 = rowstart[i + 1];         // both mult of 8
        for (int e = e0; e < e1; e += 8) {
            u16x8 cc = *(const u16x8*)(colidx + e);         // 16B, aligned
            unsigned u[8];
#pragma unroll
            for (int j = 0; j < 8; ++j)
                u[j] = Gh[(size_t)cc[j] * 64 + lane];
#pragma unroll
            for (int j = 0; j < 8; ++j) {
                float2 v = h2f(u[j]);
                acc.x += v.x;
                acc.y += v.y;
            }
        }
        float hx = fmaxf(fmaf(di, acc.x, bx), 0.f) * di;    // H'' = dinv*relu
        float hy = fmaxf(fmaf(di, acc.y, by), 0.f) * di;
        Hh[(size_t)i * 64 + lane] = f2h(hx, hy);
    }
}

// --- agg2 + pool: pool[batch_i] += dinv_i*(sum_e H''_s + H''_i) -------------
__global__ __launch_bounds__(256) void agg2_pool_kernel(const unsigned* __restrict__ Hh,
                                                        const int* __restrict__ rowstart,
                                                        const unsigned short* __restrict__ colidx,
                                                        const float* __restrict__ dinv,
                                                        const int* __restrict__ batch,
                                                        float* __restrict__ pool,
                                                        int N, int chunk) {
    int gid  = blockIdx.x * 4 + (threadIdx.x >> 6);
    int lane = threadIdx.x & 63;
    int i0 = gid * chunk, i1 = min(i0 + chunk, N);
    if (i0 >= N) return;

    float2 pa = make_float2(0.f, 0.f);
    int cur = min(max(batch[i0], 0), NGRAPH - 1);
    for (int i = i0; i < i1; ++i) {
        float di = dinv[i];
        float2 a = h2f(Hh[(size_t)i * 64 + lane]);          // self term
        int e0 = rowstart[i], e1 = rowstart[i + 1];
        for (int e = e0; e < e1; e += 8) {
            u16x8 cc = *(const u16x8*)(colidx + e);
            unsigned u[8];
#pragma unroll
            for (int j = 0; j < 8; ++j)
                u[j] = Hh[(size_t)cc[j] * 64 + lane];
#pragma unroll
            for (int j = 0; j < 8; ++j) {
                float2 v = h2f(u[j]);
                a.x += v.x;
                a.y += v.y;
            }
        }
        int b = min(max(batch[i], 0), NGRAPH - 1);
        if (b != cur) {                                     // uniform per wave
            atomicAdd(&pool[(size_t)cur * D + 2 * lane], pa.x);
            atomicAdd(&pool[(size_t)cur * D + 2 * lane + 1], pa.y);
            pa = make_float2(0.f, 0.f);
            cur = b;
        }
        pa.x = fmaf(di, a.x, pa.x);
        pa.y = fmaf(di, a.y, pa.y);
    }
    atomicAdd(&pool[(size_t)cur * D + 2 * lane], pa.x);
    atomicAdd(&pool[(size_t)cur * D + 2 * lane + 1], pa.y);
}

// --- Final tiny GEMM: out[g][o] = (pool[g]/cnt_g) . W2[:,o] + b2[o] ---------
__device__ __forceinline__ int lbound(const int* __restrict__ a, int n, int v) {
    int lo = 0, hi = n;
    while (lo < hi) {
        int m = (lo + hi) >> 1;
        if (a[m] < v) lo = m + 1; else hi = m;
    }
    return lo;
}

__global__ void final_gemm_kernel(const float* __restrict__ pool,
                                  const int* __restrict__ batch,
                                  const float* __restrict__ W2,
                                  const float* __restrict__ b2,
                                  float* __restrict__ out, int N) {
    int g = blockIdx.x, o = threadIdx.x;
    int s = lbound(batch, N, g);
    int e = lbound(batch, N, g + 1);
    float inv_cnt = 1.0f / fmaxf((float)(e - s), 1.0f);
    float acc = 0.f;
#pragma unroll 4
    for (int k = 0; k < D; ++k)
        acc = fmaf(pool[g * D + k], W2[k * D + o], acc);
    out[g * D + o] = acc * inv_cnt + b2[o];
}

// ---------------------------------------------------------------------------

extern "C" void kernel_launch(void* const* d_in, const int* in_sizes, int n_in,
                              void* d_out, int out_size, void* d_ws, size_t ws_size,
                              hipStream_t stream) {
    const float* x     = (const float*)d_in[0];
    const int*   ei    = (const int*)  d_in[1];
    const int*   batch = (const int*)  d_in[2];
    const float* W1    = (const float*)d_in[3];
    const float* b1    = (const float*)d_in[4];
    const float* W2    = (const float*)d_in[5];
    const float* b2    = (const float*)d_in[6];
    float* out = (float*)d_out;

    const int N = in_sizes[0] / D;
    const int E = in_sizes[1] / 2;
    const int nbuck = (N + BUCK_W - 1) >> BUCK_SH;      // <=128 for N<=65536
    const int CAP   = (E / (nbuck > 0 ? nbuck : 1)) * 2 + 1024;

    // workspace carve-up (256B aligned); bcnt+pool adjacent -> single memset
    char* ws = (char*)d_ws;
    size_t off = 0;
    auto carve = [&](size_t bytes) {
        size_t o = off;
        off = (off + bytes + 255) & ~(size_t)255;
        return o;
    };
    size_t o_bcnt     = carve((size_t)MAXBUCK * 4);
    size_t o_pool     = carve((size_t)NGRAPH * D * 4);
    size_t zspan      = off;                       // memset [0, zspan)
    size_t o_rowstart = carve((size_t)(N + 1) * 4);
    size_t o_deg      = carve((size_t)N * 4);
    size_t o_dinv     = carve((size_t)N * 4);
    size_t o_padsum   = carve((size_t)MAXBUCK * 4);
    size_t o_bbase    = carve((size_t)MAXBUCK * 4);
    size_t o_colidx   = carve(((size_t)E + 7 * (size_t)N + 64) * 2);  // padded
    size_t o_buck     = carve((size_t)nbuck * CAP * 4);
    size_t o_wb       = carve((size_t)D * D * 2);        // fp16 W1 (MFMA B)
    size_t o_gh       = carve((size_t)(N + 1) * D * 2);  // fp16 G' (+zero row)
    size_t o_hh       = carve((size_t)(N + 1) * D * 2);  // fp16 H'' (+zero row)
    size_t need = off;

    if (ws_size < need) {
        zero_out_kernel<<<(out_size + 255) / 256, 256, 0, stream>>>(out, out_size);
        return;
    }

    int*            bcnt     = (int*)           (ws + o_bcnt);
    float*          pool     = (float*)         (ws + o_pool);
    int*            rowstart = (int*)           (ws + o_rowstart);
    int*            deg      = (int*)           (ws + o_deg);
    float*          dinv     = (float*)         (ws + o_dinv);
    int*            padsum   = (int*)           (ws + o_padsum);
    int*            bbase    = (int*)           (ws + o_bbase);
    unsigned short* colidx   = (unsigned short*)(ws + o_colidx);
    unsigned*       buck     = (unsigned*)      (ws + o_buck);
    _Float16*       WB       = (_Float16*)      (ws + o_wb);
    _Float16*       Gh       = (_Float16*)      (ws + o_gh);
    _Float16*       Hh       = (_Float16*)      (ws + o_hh);

    hipMemsetAsync(ws, 0, zspan, stream);          // bcnt + pool in one shot

    int ebs = (E + 1023) / 1024;                   // scatter: 4 edges/thread
    int gb  = (N + 63) / 64;

    pack_scatter_kernel<<<9 + ebs, 256, 0, stream>>>(W1, WB, ei, bcnt, buck,
                                                     (unsigned*)Gh, (unsigned*)Hh,
                                                     N, E, CAP);
    bucket_deg_kernel<<<nbuck, 256, 0, stream>>>(buck, bcnt, deg, dinv, padsum, N, CAP);
    bucket_scan_kernel<<<1, 128, 0, stream>>>(padsum, bbase, rowstart, N, nbuck);
    gemm_fill_kernel<<<gb + nbuck, 256, 0, stream>>>(x, WB, dinv, Gh, buck, bcnt,
                                                     deg, bbase, rowstart, colidx,
                                                     N, CAP, gb);

    int groups = AGG_BLOCKS * 4;
    int chunk  = (N + groups - 1) / groups;
    agg1_kernel<<<AGG_BLOCKS, 256, 0, stream>>>((const unsigned*)Gh, rowstart, colidx,
                                                dinv, b1, (unsigned*)Hh, N, chunk);
    agg2_pool_kernel<<<AGG_BLOCKS, 256, 0, stream>>>((const unsigned*)Hh, rowstart, colidx,
                                                     dinv, batch, pool, N, chunk);
    final_gemm_kernel<<<NGRAPH, D, 0, stream>>>(pool, batch, W2, b2, out, N);
}